// Round 6
// baseline (421.020 us; speedup 1.0000x reference)
//
#include <hip/hip_runtime.h>
#include <hip/hip_cooperative_groups.h>
#include <stdint.h>

namespace cg = cooperative_groups;

/* AdditiveAttention (B=4, Q=256, K=1024, D=512, H=256)
 * out[b,i,v] = sum_j softmax_j(sum_h tanh(q[b,i,h]+k[b,j,h])*wv[h]) * values[b,j,v],
 * masked to j < valid_lens[b].  OUTPUT IS FLOAT32 (R20 finding).
 *
 * R26: cooperative mega-kernel. Evidence: "rest" (total - attn) was
 * 143/115/106/106/155/141us across SIX different proj implementations —
 * proj micro-structure barely moves it, and proj never shows in top-5
 * counters (every dispatch < 103us). Either inter-kernel launch overhead
 * dominates, or proj is ~100us for unmodeled reasons. One cooperative
 * kernel with grid.sync() between phases kills launch gaps AND makes the
 * whole pipeline visible in one dispatch's counters.
 *   Phase 0: W -> WT [d4][256h] transpose (prescale 2*log2e folded).
 *   Phase A: proj. 1 busy wave/SIMD (1024 busy waves), 5 rows x 256 h each:
 *            lane=h, WT coalesced float4, x broadcast ds_read_b128 from LDS,
 *            80 FMA per d4. kp stores via 20KB LDS transpose (k-contiguous).
 *   Phase B: R5 attn body verbatim (proven 103us).
 * LDS: union(proj 60KB, attn 54KB) = 60KB, 1 block/CU.
 * Fallback: if hipLaunchCooperativeKernel fails, launch the R3-config
 * 3-kernel pipeline. */

#define NB 4
#define NQ 256
#define NK 1024
#define ND 512
#define NH 256
#define QROWS 4

#define C2L2E 2.8853900817779268f   /* 2*log2(e) */
#define L2E   1.4426950408889634f   /* log2(e)   */

/* 8-class valid_lens decode: {i32,i64,f32,f64,i16,f16,bf16,fallback}. */
__device__ void ff_vldec(const int* p, int* v) {
  bool ok = true;
  for (int i = 0; i < 4; ++i) { int x = p[i]; if (x < 1 || x > NK) ok = false; }
  if (ok) { for (int i = 0; i < 4; ++i) v[i] = p[i]; return; }
  ok = true;
  for (int i = 0; i < 4; ++i) {
    if (p[2 * i + 1] != 0) ok = false;
    int x = p[2 * i]; if (x < 1 || x > NK) ok = false;
  }
  if (ok) { for (int i = 0; i < 4; ++i) v[i] = p[2 * i]; return; }
  ok = true;
  for (int i = 0; i < 4; ++i) {
    union { int i; float f; } u; u.i = p[i];
    if (!(u.f >= 1.0f && u.f <= 1024.0f && u.f == floorf(u.f))) ok = false;
  }
  if (ok) {
    for (int i = 0; i < 4; ++i) { union { int i; float f; } u; u.i = p[i]; v[i] = (int)u.f; }
    return;
  }
  ok = true;
  for (int i = 0; i < 4; ++i) {
    union { long long l; double d; } u;
    u.l = ((long long)p[2 * i + 1] << 32) | (unsigned int)p[2 * i];
    if (!(u.d >= 1.0 && u.d <= 1024.0 && u.d == floor(u.d))) ok = false;
  }
  if (ok) {
    for (int i = 0; i < 4; ++i) {
      union { long long l; double d; } u;
      u.l = ((long long)p[2 * i + 1] << 32) | (unsigned int)p[2 * i];
      v[i] = (int)u.d;
    }
    return;
  }
  const uint16_t* hh = (const uint16_t*)p;
  const short*    s  = (const short*)p;
  ok = true;
  for (int i = 0; i < 4; ++i) { int x = s[i]; if (x < 1 || x > NK) ok = false; }
  if (ok) { for (int i = 0; i < 4; ++i) v[i] = s[i]; return; }
  ok = true;
  for (int i = 0; i < 4; ++i) {
    union { uint16_t u; _Float16 h; } u; u.u = hh[i];
    float f = (float)u.h;
    if (!(f >= 1.0f && f <= 1024.0f && f == floorf(f))) ok = false;
  }
  if (ok) {
    for (int i = 0; i < 4; ++i) {
      union { uint16_t u; _Float16 h; } u; u.u = hh[i];
      v[i] = (int)(float)u.h;
    }
    return;
  }
  ok = true;
  for (int i = 0; i < 4; ++i) {
    union { uint32_t u; float f; } u; u.u = ((uint32_t)hh[i]) << 16;
    if (!(u.f >= 1.0f && u.f <= 1028.0f)) ok = false;
  }
  if (ok) {
    for (int i = 0; i < 4; ++i) {
      union { uint32_t u; float f; } u; u.u = ((uint32_t)hh[i]) << 16;
      int x = (int)(u.f + 0.5f); if (x > NK) x = NK; v[i] = x;
    }
    return;
  }
  for (int i = 0; i < 4; ++i) v[i] = NK;  /* fail-safe: unmasked */
}

union ProjAttnLds {
  struct { float xs[20 * ND]; float trans[20 * NH]; } pj;           /* 60 KB */
  struct {
    float qs[NH * QROWS]; float ws[NH]; float st[NK * QROWS];
    float pm[16]; float psm[16]; float part[4 * QROWS * ND];
  } at;                                                             /* 53.1 KB */
};

/* Proj inner: rows [rlo,rhi) of this task against one WT.  Literal (0,5)
 * calls constant-fold the guards; only the 1 straddling task pays them. */
__device__ __forceinline__ void projPass(
    const float4* __restrict__ wt4, const float4* __restrict__ xs4,
    int L, int rlo, int rhi, float (&acc)[5][4])
{
  #pragma unroll 2
  for (int d4 = 0; d4 < ND / 4; ++d4) {
    const float4* wp = wt4 + (size_t)d4 * NH + L;
    float4 w0 = wp[0], w1 = wp[64], w2 = wp[128], w3 = wp[192];
    #pragma unroll
    for (int r = 0; r < 5; ++r) {
      if (r >= rlo && r < rhi) {
        float4 x = xs4[r * 128 + d4];
        acc[r][0] += w0.x*x.x + w0.y*x.y + w0.z*x.z + w0.w*x.w;
        acc[r][1] += w1.x*x.x + w1.y*x.y + w1.z*x.z + w1.w*x.w;
        acc[r][2] += w2.x*x.x + w2.y*x.y + w2.z*x.z + w2.w*x.w;
        acc[r][3] += w3.x*x.x + w3.y*x.y + w3.z*x.z + w3.w*x.w;
      }
    }
  }
}

__global__ __launch_bounds__(1024) void ff_mega(
    const float* __restrict__ queries, const float* __restrict__ keys,
    const float* __restrict__ values, const int* __restrict__ vlraw,
    const float* __restrict__ Wq, const float* __restrict__ Wk,
    const float* __restrict__ wvp, float* __restrict__ out,
    float* __restrict__ qp, float* __restrict__ kp,
    float* __restrict__ wtq, float* __restrict__ wtk)
{
  __shared__ ProjAttnLds sm;
  const int t  = threadIdx.x;
  const int bi = blockIdx.x;

  /* ---- phase 0: WT build (blocks 0..63) ---- */
  {
    const int gid = bi * 1024 + t;
    if (gid < 2 * (ND / 4) * NH) {
      const int m = gid >> 15, idx = gid & 32767;
      const int d4 = idx & 127, h = idx >> 7;
      const float* src = m ? Wk : Wq;
      float*       dst = m ? wtk : wtq;
      float4 w = *(const float4*)(src + (size_t)h * ND + d4 * 4);
      w.x *= C2L2E; w.y *= C2L2E; w.z *= C2L2E; w.w *= C2L2E;
      *(float4*)(dst + ((size_t)d4 * NH + h) * 4) = w;
    }
  }

  /* ---- stage this block's 20 rows into xs ---- */
  const int blk_r0 = bi * 20;
  #pragma unroll
  for (int i = 0; i < 3; ++i) {
    int f = t + 1024 * i;
    if (f < 20 * ND / 4) {
      int lr = f >> 7, d4 = f & 127;
      int gr = blk_r0 + lr;
      const float* src = (gr < 1024) ? (queries + (size_t)gr * ND)
                                     : (keys + (size_t)(gr - 1024) * ND);
      ((float4*)sm.pj.xs)[lr * 128 + d4] = ((const float4*)src)[d4];
    }
  }
  __syncthreads();
  cg::this_grid().sync();                 /* WT visible everywhere */

  /* ---- phase A: projection, 1 busy wave per SIMD ---- */
  const int wid = t >> 6, L = t & 63;
  if ((wid & 3) == 0) {
    const int task = bi * 4 + (wid >> 2);
    const int r0 = task * 5;
    int nq = 1024 - r0; nq = nq < 0 ? 0 : (nq > 5 ? 5 : nq);
    const int lrow0 = r0 - blk_r0;
    float acc[5][4];
    #pragma unroll
    for (int r = 0; r < 5; ++r)
      #pragma unroll
      for (int c = 0; c < 4; ++c) acc[r][c] = 0.f;

    const float4* xs4 = (const float4*)sm.pj.xs + (size_t)lrow0 * 128;
    if (nq == 5)      projPass((const float4*)wtq, xs4, L, 0, 5, acc);
    else if (nq == 0) projPass((const float4*)wtk, xs4, L, 0, 5, acc);
    else {
      projPass((const float4*)wtq, xs4, L, 0, nq, acc);
      projPass((const float4*)wtk, xs4, L, nq, 5, acc);
    }

    #pragma unroll
    for (int r = 0; r < 5; ++r) {
      const int gr = r0 + r;
      if (gr < 1024) {            /* q-row: direct coalesced store */
        float* o = qp + (size_t)gr * NH + L;
        o[0] = acc[r][0]; o[64] = acc[r][1]; o[128] = acc[r][2]; o[192] = acc[r][3];
      } else {                    /* k-row: via LDS transpose */
        float* o = &sm.pj.trans[(size_t)(lrow0 + r) * NH + L];
        o[0] = acc[r][0]; o[64] = acc[r][1]; o[128] = acc[r][2]; o[192] = acc[r][3];
      }
    }
  }
  __syncthreads();

  /* k-row store: lanes along k (4 consecutive k per 4-thread group) */
  {
    const int h = t >> 2, ks = t & 3;
    #pragma unroll
    for (int i = 0; i < 5; ++i) {
      int kl = ks + 4 * i;
      int gr = blk_r0 + kl;
      if (gr >= 1024) {
        int g = gr - 1024, bb = g >> 10, k = g & 1023;
        kp[(size_t)bb * NH * NK + (size_t)h * NK + k] = sm.pj.trans[kl * NH + h];
      }
    }
  }
  __threadfence();
  cg::this_grid().sync();                 /* qp/kp visible everywhere */

  /* ---- phase B: attention (R5 body, proven) ---- */
  const int q0 = (bi & 63) * QROWS;
  const int b  = bi >> 6;

  {
    const float* qsrc = qp + ((size_t)b * NQ + q0) * NH;
    const int row = t >> 8, h = t & 255;
    sm.at.qs[h * QROWS + row] = qsrc[t];
    if (t < NH) sm.at.ws[t] = -2.0f * wvp[t];
  }
  __syncthreads();

  int vls[4];
  ff_vldec(vlraw, vls);
  const int vl = vls[b];

  float a0 = 0.f, a1 = 0.f, a2 = 0.f, a3 = 0.f;
  {
    const float* kvp = kp + (size_t)b * NH * NK + t;
    #pragma unroll 8
    for (int h = 0; h < NH; ++h) {
      float  kv = kvp[(size_t)h * NK];
      float4 q4 = *(const float4*)(sm.at.qs + h * QROWS);
      float  w  = sm.at.ws[h];
      a0 += w * __builtin_amdgcn_rcpf(1.0f + __builtin_amdgcn_exp2f(q4.x + kv));
      a1 += w * __builtin_amdgcn_rcpf(1.0f + __builtin_amdgcn_exp2f(q4.y + kv));
      a2 += w * __builtin_amdgcn_rcpf(1.0f + __builtin_amdgcn_exp2f(q4.z + kv));
      a3 += w * __builtin_amdgcn_rcpf(1.0f + __builtin_amdgcn_exp2f(q4.w + kv));
    }
  }
  {
    const bool okm = (t < vl);
    *(float4*)&sm.at.st[t * 4] = make_float4(okm ? a0 : -1e6f, okm ? a1 : -1e6f,
                                             okm ? a2 : -1e6f, okm ? a3 : -1e6f);
  }
  __syncthreads();

  {
    const int wd = t >> 6, lane = t & 63;
    const int row = wd >> 2, seg = wd & 3;
    const int kb = seg * 256 + lane;
    float v0 = sm.at.st[(kb      ) * 4 + row];
    float v1 = sm.at.st[(kb +  64) * 4 + row];
    float v2 = sm.at.st[(kb + 128) * 4 + row];
    float v3 = sm.at.st[(kb + 192) * 4 + row];
    float m = fmaxf(fmaxf(v0, v1), fmaxf(v2, v3));
    for (int o = 32; o; o >>= 1) m = fmaxf(m, __shfl_xor(m, o));
    if (lane == 0) sm.at.pm[wd] = m;
    __syncthreads();
    m = fmaxf(fmaxf(sm.at.pm[row*4+0], sm.at.pm[row*4+1]),
              fmaxf(sm.at.pm[row*4+2], sm.at.pm[row*4+3]));
    float e0 = __builtin_amdgcn_exp2f((v0 - m) * L2E);
    float e1 = __builtin_amdgcn_exp2f((v1 - m) * L2E);
    float e2 = __builtin_amdgcn_exp2f((v2 - m) * L2E);
    float e3 = __builtin_amdgcn_exp2f((v3 - m) * L2E);
    float smm = e0 + e1 + e2 + e3;
    for (int o = 32; o; o >>= 1) smm += __shfl_xor(smm, o);
    if (lane == 0) sm.at.psm[wd] = smm;
    __syncthreads();
    const float S = sm.at.psm[row*4+0] + sm.at.psm[row*4+1]
                  + sm.at.psm[row*4+2] + sm.at.psm[row*4+3];
    const float rr = 1.0f / S;
    sm.at.st[(kb      ) * 4 + row] = e0 * rr;
    sm.at.st[(kb +  64) * 4 + row] = e1 * rr;
    sm.at.st[(kb + 128) * 4 + row] = e2 * rr;
    sm.at.st[(kb + 192) * 4 + row] = e3 * rr;
  }
  __syncthreads();

  {
    const int kq = t >> 8, c2 = (t & 255) * 2;
    const float* vb = values + (size_t)b * NK * ND + c2;
    float ox0=0.f, oy0=0.f, ox1=0.f, oy1=0.f;
    float ox2=0.f, oy2=0.f, ox3=0.f, oy3=0.f;
    const int k0 = kq * 256;
    #pragma unroll 8
    for (int k = k0; k < k0 + 256; ++k) {
      float2 v2 = *(const float2*)(vb + (size_t)k * ND);
      float4 a  = *(const float4*)&sm.at.st[k * 4];
      ox0 += a.x * v2.x; oy0 += a.x * v2.y;
      ox1 += a.y * v2.x; oy1 += a.y * v2.y;
      ox2 += a.z * v2.x; oy2 += a.z * v2.y;
      ox3 += a.w * v2.x; oy3 += a.w * v2.y;
    }
    float* pp = &sm.at.part[(size_t)kq * QROWS * ND + c2];
    *(float2*)(pp         ) = make_float2(ox0, oy0);
    *(float2*)(pp +     ND) = make_float2(ox1, oy1);
    *(float2*)(pp + 2 * ND) = make_float2(ox2, oy2);
    *(float2*)(pp + 3 * ND) = make_float2(ox3, oy3);
  }
  __syncthreads();
  {
    const int r = t >> 8, c2 = (t & 255) * 2;
    const float* pp = &sm.at.part[(size_t)r * ND + c2];
    float2 s = make_float2(0.f, 0.f);
    #pragma unroll
    for (int kq = 0; kq < 4; ++kq) {
      float2 p = *(const float2*)(pp + (size_t)kq * QROWS * ND);
      s.x += p.x; s.y += p.y;
    }
    *(float2*)(out + ((size_t)b * NQ + q0 + r) * ND + c2) = s;
  }
}

/* ================= fallback (R3-config 3-kernel pipeline) ================= */

__global__ __launch_bounds__(256) void ff_wt(
    const float* __restrict__ Wq, const float* __restrict__ Wk,
    float* __restrict__ WTq, float* __restrict__ WTk)
{
  const int idx = blockIdx.x * 256 + threadIdx.x;
  const int d4 = idx & 127, h = idx >> 7;
  const float* src = blockIdx.y ? Wk : Wq;
  float*       dst = blockIdx.y ? WTk : WTq;
  float4 w = *(const float4*)(src + (size_t)h * ND + d4 * 4);
  w.x *= C2L2E; w.y *= C2L2E; w.z *= C2L2E; w.w *= C2L2E;
  *(float4*)(dst + ((size_t)d4 * NH + h) * 4) = w;
}

__global__ __launch_bounds__(256) void ff_proj(
    const float* __restrict__ q_in, const float* __restrict__ k_in,
    const float* __restrict__ WTq, const float* __restrict__ WTk,
    float* __restrict__ qp, float* __restrict__ kp)
{
  __shared__ float xs[8 * ND];
  const int t = threadIdx.x;
  const bool isq = blockIdx.x < (NB * NQ / 8);
  const int g = isq ? blockIdx.x : (blockIdx.x - NB * NQ / 8);
  const float* xin = (isq ? q_in : k_in) + (size_t)g * 8 * ND;
  const float* WT  = isq ? WTq : WTk;

  #pragma unroll
  for (int i = 0; i < 4; ++i)
    ((float4*)xs)[t + 256 * i] = ((const float4*)xin)[t + 256 * i];
  __syncthreads();

  float acc[8];
  #pragma unroll
  for (int r = 0; r < 8; ++r) acc[r] = 0.f;

  #pragma unroll 2
  for (int d4 = 0; d4 < ND / 4; ++d4) {
    float4 w = *(const float4*)(WT + ((size_t)d4 * NH + t) * 4);
    #pragma unroll
    for (int r = 0; r < 8; ++r) {
      float4 x = *(const float4*)&xs[r * ND + d4 * 4];
      acc[r] += w.x * x.x + w.y * x.y + w.z * x.z + w.w * x.w;
    }
  }

  if (isq) {
    float* o = qp + (size_t)g * 8 * NH + t;
    #pragma unroll
    for (int r = 0; r < 8; ++r) o[(size_t)r * NH] = acc[r];
  } else {
    const int r0 = g * 8;
    const int bb = r0 >> 10, rk = r0 & (NK - 1);
    float* o = kp + ((size_t)bb * NH + t) * NK + rk;
    *(float4*)o       = make_float4(acc[0], acc[1], acc[2], acc[3]);
    *(float4*)(o + 4) = make_float4(acc[4], acc[5], acc[6], acc[7]);
  }
}

__global__ __launch_bounds__(1024) void ff_attn(
    const float* __restrict__ qp, const float* __restrict__ kp,
    const float* __restrict__ vals, const int* __restrict__ vlraw,
    const float* __restrict__ wvp, float* __restrict__ out)
{
  __shared__ float qs[NH * QROWS];
  __shared__ float ws[NH];
  __shared__ float st[NK * QROWS];
  __shared__ float pm[16], psm[16];
  __shared__ float part[4 * QROWS * ND];

  const int t  = threadIdx.x;
  const int q0 = blockIdx.x * QROWS;
  const int b  = blockIdx.y;

  {
    const float* qsrc = qp + ((size_t)b * NQ + q0) * NH;
    const int row = t >> 8, h = t & 255;
    qs[h * QROWS + row] = qsrc[t];
    if (t < NH) ws[t] = -2.0f * wvp[t];
  }
  __syncthreads();

  int vls[4];
  ff_vldec(vlraw, vls);
  const int vl = vls[b];

  float a0 = 0.f, a1 = 0.f, a2 = 0.f, a3 = 0.f;
  {
    const float* kvp = kp + (size_t)b * NH * NK + t;
    #pragma unroll 8
    for (int h = 0; h < NH; ++h) {
      float  kv = kvp[(size_t)h * NK];
      float4 q4 = *(const float4*)(qs + h * QROWS);
      float  w  = ws[h];
      a0 += w * __builtin_amdgcn_rcpf(1.0f + __builtin_amdgcn_exp2f(q4.x + kv));
      a1 += w * __builtin_amdgcn_rcpf(1.0f + __builtin_amdgcn_exp2f(q4.y + kv));
      a2 += w * __builtin_amdgcn_rcpf(1.0f + __builtin_amdgcn_exp2f(q4.z + kv));
      a3 += w * __builtin_amdgcn_rcpf(1.0f + __builtin_amdgcn_exp2f(q4.w + kv));
    }
  }
  {
    const bool okm = (t < vl);
    *(float4*)&st[t * 4] = make_float4(okm ? a0 : -1e6f, okm ? a1 : -1e6f,
                                       okm ? a2 : -1e6f, okm ? a3 : -1e6f);
  }
  __syncthreads();

  {
    const int wd = t >> 6, lane = t & 63;
    const int row = wd >> 2, seg = wd & 3;
    const int kb = seg * 256 + lane;
    float v0 = st[(kb      ) * 4 + row];
    float v1 = st[(kb +  64) * 4 + row];
    float v2 = st[(kb + 128) * 4 + row];
    float v3 = st[(kb + 192) * 4 + row];
    float m = fmaxf(fmaxf(v0, v1), fmaxf(v2, v3));
    for (int o = 32; o; o >>= 1) m = fmaxf(m, __shfl_xor(m, o));
    if (lane == 0) pm[wd] = m;
    __syncthreads();
    m = fmaxf(fmaxf(pm[row*4+0], pm[row*4+1]), fmaxf(pm[row*4+2], pm[row*4+3]));
    float e0 = __builtin_amdgcn_exp2f((v0 - m) * L2E);
    float e1 = __builtin_amdgcn_exp2f((v1 - m) * L2E);
    float e2 = __builtin_amdgcn_exp2f((v2 - m) * L2E);
    float e3 = __builtin_amdgcn_exp2f((v3 - m) * L2E);
    float smm = e0 + e1 + e2 + e3;
    for (int o = 32; o; o >>= 1) smm += __shfl_xor(smm, o);
    if (lane == 0) psm[wd] = smm;
    __syncthreads();
    const float S = psm[row*4+0] + psm[row*4+1] + psm[row*4+2] + psm[row*4+3];
    const float rr = 1.0f / S;
    st[(kb      ) * 4 + row] = e0 * rr;
    st[(kb +  64) * 4 + row] = e1 * rr;
    st[(kb + 128) * 4 + row] = e2 * rr;
    st[(kb + 192) * 4 + row] = e3 * rr;
  }
  __syncthreads();

  {
    const int kq = t >> 8, c2 = (t & 255) * 2;
    const float* vb = vals + (size_t)b * NK * ND + c2;
    float ox0=0.f, oy0=0.f, ox1=0.f, oy1=0.f;
    float ox2=0.f, oy2=0.f, ox3=0.f, oy3=0.f;
    const int k0 = kq * 256;
    #pragma unroll 8
    for (int k = k0; k < k0 + 256; ++k) {
      float2 v2 = *(const float2*)(vb + (size_t)k * ND);
      float4 a  = *(const float4*)&st[k * 4];
      ox0 += a.x * v2.x; oy0 += a.x * v2.y;
      ox1 += a.y * v2.x; oy1 += a.y * v2.y;
      ox2 += a.z * v2.x; oy2 += a.z * v2.y;
      ox3 += a.w * v2.x; oy3 += a.w * v2.y;
    }
    float* pp = &part[(size_t)kq * QROWS * ND + c2];
    *(float2*)(pp         ) = make_float2(ox0, oy0);
    *(float2*)(pp +     ND) = make_float2(ox1, oy1);
    *(float2*)(pp + 2 * ND) = make_float2(ox2, oy2);
    *(float2*)(pp + 3 * ND) = make_float2(ox3, oy3);
  }
  __syncthreads();
  {
    const int r = t >> 8, c2 = (t & 255) * 2;
    const float* pp = &part[(size_t)r * ND + c2];
    float2 s = make_float2(0.f, 0.f);
    #pragma unroll
    for (int kq = 0; kq < 4; ++kq) {
      float2 p = *(const float2*)(pp + (size_t)kq * QROWS * ND);
      s.x += p.x; s.y += p.y;
    }
    *(float2*)(out + ((size_t)b * NQ + q0 + r) * ND + c2) = s;
  }
}

extern "C" void kernel_launch(void* const* d_in, const int* in_sizes, int n_in,
                              void* d_out, int out_size, void* d_ws, size_t ws_size,
                              hipStream_t stream) {
  const float* queries = (const float*)d_in[0];
  const float* keys    = (const float*)d_in[1];
  const float* values  = (const float*)d_in[2];
  const int*   vlens   = (const int*)d_in[3];
  const float* Wq      = (const float*)d_in[4];
  const float* Wk      = (const float*)d_in[5];
  const float* wv      = (const float*)d_in[6];
  float* out = (float*)d_out;               /* F32 OUTPUT */

  float* qp  = (float*)d_ws;                /* [B][Q][H]   1 MB, pre-scaled */
  float* kp  = qp  + (size_t)NB * NQ * NH;  /* [B][H][K]   4 MB, pre-scaled */
  float* wtq = kp  + (size_t)NB * NH * NK;  /* [D/4][H]x4  512 KB */
  float* wtk = wtq + (size_t)(ND / 4) * NH * 4; /*         512 KB */

  void* args[] = { (void*)&queries, (void*)&keys, (void*)&values, (void*)&vlens,
                   (void*)&Wq, (void*)&Wk, (void*)&wv, (void*)&out,
                   (void*)&qp, (void*)&kp, (void*)&wtq, (void*)&wtk };
  hipError_t e = hipLaunchCooperativeKernel((const void*)ff_mega,
                                            dim3(256), dim3(1024),
                                            args, 0, stream);
  if (e != hipSuccess) {
    (void)hipGetLastError();   /* clear, fall back to 3-kernel pipeline */
    ff_wt  <<<dim3(128, 2), 256, 0, stream>>>(Wq, Wk, wtq, wtk);
    ff_proj<<<dim3(NB * NQ / 8 + NB * NK / 8), 256, 0, stream>>>(
        queries, keys, wtq, wtk, qp, kp);
    ff_attn<<<dim3(NQ / QROWS, NB), 1024, 0, stream>>>(qp, kp, values, vlens, wv, out);
  }
}

// Round 7
// 195.660 us; speedup vs baseline: 2.1518x; 2.1518x over previous
//
#include <hip/hip_runtime.h>
#include <stdint.h>

/* AdditiveAttention (B=4, Q=256, K=1024, D=512, H=256)
 * out[b,i,v] = sum_j softmax_j(sum_h tanh(q[b,i,h]+k[b,j,h])*wv[h]) * values[b,j,v],
 * masked to j < valid_lens[b].  OUTPUT IS FLOAT32 (R20 finding).
 *
 * R27: mega-kernel (R26, 343us) revealed fixed harness overhead ~78us
 * (single-dispatch total 421 - kernel 343). Recast history: proj+wt was
 * ~29us at 2.5 waves/SIMD (R2/R3), ~63us at 1.25 (R5), ~230us at 1 busy
 * wave/SIMD (mega) -> proj is LATENCY-bound, scales with occupancy.
 * (a) proj: 1280 blocks (16 rows x 64-h tile, 256thr, 32KB LDS -> 5
 * blocks/CU = 5 waves/SIMD). Per d4: 1 coalesced WT float4 + 4 broadcast
 * ds_read_b128 + 16 FMA. (b) attn: R5 structure EXACT, arithmetic in P1/P3
 * grouped as ext_vector float2 so backend emits v_pk_add/fma_f32 (VOP3P).
 * (c) coop mega dropped. */

#define NB 4
#define NQ 256
#define NK 1024
#define ND 512
#define NH 256
#define QROWS 4
#define PJR 16
#define PJH 64

#define C2L2E 2.8853900817779268f   /* 2*log2(e) */
#define L2E   1.4426950408889634f   /* log2(e)   */

typedef float v2f __attribute__((ext_vector_type(2)));

/* 8-class valid_lens decode: {i32,i64,f32,f64,i16,f16,bf16,fallback}. */
__device__ void ff_vldec(const int* p, int* v) {
  bool ok = true;
  for (int i = 0; i < 4; ++i) { int x = p[i]; if (x < 1 || x > NK) ok = false; }
  if (ok) { for (int i = 0; i < 4; ++i) v[i] = p[i]; return; }
  ok = true;
  for (int i = 0; i < 4; ++i) {
    if (p[2 * i + 1] != 0) ok = false;
    int x = p[2 * i]; if (x < 1 || x > NK) ok = false;
  }
  if (ok) { for (int i = 0; i < 4; ++i) v[i] = p[2 * i]; return; }
  ok = true;
  for (int i = 0; i < 4; ++i) {
    union { int i; float f; } u; u.i = p[i];
    if (!(u.f >= 1.0f && u.f <= 1024.0f && u.f == floorf(u.f))) ok = false;
  }
  if (ok) {
    for (int i = 0; i < 4; ++i) { union { int i; float f; } u; u.i = p[i]; v[i] = (int)u.f; }
    return;
  }
  ok = true;
  for (int i = 0; i < 4; ++i) {
    union { long long l; double d; } u;
    u.l = ((long long)p[2 * i + 1] << 32) | (unsigned int)p[2 * i];
    if (!(u.d >= 1.0 && u.d <= 1024.0 && u.d == floor(u.d))) ok = false;
  }
  if (ok) {
    for (int i = 0; i < 4; ++i) {
      union { long long l; double d; } u;
      u.l = ((long long)p[2 * i + 1] << 32) | (unsigned int)p[2 * i];
      v[i] = (int)u.d;
    }
    return;
  }
  const uint16_t* hh = (const uint16_t*)p;
  const short*    s  = (const short*)p;
  ok = true;
  for (int i = 0; i < 4; ++i) { int x = s[i]; if (x < 1 || x > NK) ok = false; }
  if (ok) { for (int i = 0; i < 4; ++i) v[i] = s[i]; return; }
  ok = true;
  for (int i = 0; i < 4; ++i) {
    union { uint16_t u; _Float16 h; } u; u.u = hh[i];
    float f = (float)u.h;
    if (!(f >= 1.0f && f <= 1024.0f && f == floorf(f))) ok = false;
  }
  if (ok) {
    for (int i = 0; i < 4; ++i) {
      union { uint16_t u; _Float16 h; } u; u.u = hh[i];
      v[i] = (int)(float)u.h;
    }
    return;
  }
  ok = true;
  for (int i = 0; i < 4; ++i) {
    union { uint32_t u; float f; } u; u.u = ((uint32_t)hh[i]) << 16;
    if (!(u.f >= 1.0f && u.f <= 1028.0f)) ok = false;
  }
  if (ok) {
    for (int i = 0; i < 4; ++i) {
      union { uint32_t u; float f; } u; u.u = ((uint32_t)hh[i]) << 16;
      int x = (int)(u.f + 0.5f); if (x > NK) x = NK; v[i] = x;
    }
    return;
  }
  for (int i = 0; i < 4; ++i) v[i] = NK;  /* fail-safe: unmasked */
}

/* Transpose W[h][d] -> WT float4 #(d4*NH+h) = C2L2E * W[h][4d4..4d4+3]. */
__global__ __launch_bounds__(256) void ff_wt(
    const float* __restrict__ Wq, const float* __restrict__ Wk,
    float* __restrict__ WTq, float* __restrict__ WTk)
{
  const int idx = blockIdx.x * 256 + threadIdx.x;   /* 0..32767 */
  const int d4 = idx & 127, h = idx >> 7;
  const float* src = blockIdx.y ? Wk : Wq;
  float*       dst = blockIdx.y ? WTk : WTq;
  float4 w = *(const float4*)(src + (size_t)h * ND + d4 * 4);
  w.x *= C2L2E; w.y *= C2L2E; w.z *= C2L2E; w.w *= C2L2E;
  *(float4*)(dst + ((size_t)d4 * NH + h) * 4) = w;
}

/* Projection, occupancy-first: grid = 320 row-groups x 4 h-tiles = 1280
 * blocks, 256 thr, 32KB LDS -> 5 blocks/CU (5 waves/SIMD). Wave rw owns
 * rows 4rw..4rw+3 (broadcast ds_read); lane owns h = h0 + (t&63) (WT
 * coalesced 1KB/wave/d4). Per d4: 1 vmem f4 + 4 ds b128 + 16 FMA. */
__global__ __launch_bounds__(256) void ff_proj(
    const float* __restrict__ q_in, const float* __restrict__ k_in,
    const float* __restrict__ WTq, const float* __restrict__ WTk,
    float* __restrict__ qp, float* __restrict__ kp)
{
  __shared__ float xs[PJR * ND];                 /* 32 KB */
  const int t  = threadIdx.x;
  const int rg = blockIdx.x >> 2;                /* 0..319 */
  const int h0 = (blockIdx.x & 3) * PJH;
  const int gr0 = rg * PJR;
  const bool isq = gr0 < NB * NQ;
  const float* xin = isq ? (q_in + (size_t)gr0 * ND)
                         : (k_in + (size_t)(gr0 - NB * NQ) * ND);
  const float4* wt4 = (const float4*)(isq ? WTq : WTk);

  #pragma unroll
  for (int i = 0; i < 8; ++i)
    ((float4*)xs)[t + 256 * i] = ((const float4*)xin)[t + 256 * i];
  __syncthreads();

  const int L  = t & 63;                         /* h lane */
  const int rw = t >> 6;                         /* wave: rows 4rw..4rw+3 */
  float a0 = 0.f, a1 = 0.f, a2 = 0.f, a3 = 0.f;
  const float4* xr = (const float4*)xs + (size_t)(4 * rw) * 128;

  #pragma unroll 4
  for (int d4 = 0; d4 < ND / 4; ++d4) {
    float4 w  = wt4[(size_t)d4 * NH + h0 + L];
    float4 x0 = xr[d4];
    float4 x1 = xr[128 + d4];
    float4 x2 = xr[256 + d4];
    float4 x3 = xr[384 + d4];
    a0 += w.x*x0.x + w.y*x0.y + w.z*x0.z + w.w*x0.w;
    a1 += w.x*x1.x + w.y*x1.y + w.z*x1.z + w.w*x1.w;
    a2 += w.x*x2.x + w.y*x2.y + w.z*x2.z + w.w*x2.w;
    a3 += w.x*x3.x + w.y*x3.y + w.z*x3.z + w.w*x3.w;
  }

  const int h = h0 + L;
  if (isq) {
    float* o = qp + (size_t)(gr0 + 4 * rw) * NH + h;
    o[0] = a0; o[NH] = a1; o[2 * NH] = a2; o[3 * NH] = a3;
  } else {
    const int g = gr0 - NB * NQ + 4 * rw;        /* 4-aligned k index */
    const int bb = g >> 10, k = g & (NK - 1);
    *(float4*)(kp + ((size_t)bb * NH + h) * NK + k) = make_float4(a0, a1, a2, a3);
  }
}

/* Fused scores + masked softmax + PV.  1024 threads, 4 q-rows per block.
 * R5 structure EXACT; P1/P3 arithmetic packed as v2f (v_pk_*_f32). */
__global__ __launch_bounds__(1024) void ff_attn(
    const float* __restrict__ qp, const float* __restrict__ kp,
    const float* __restrict__ vals, const int* __restrict__ vlraw,
    const float* __restrict__ wvp, float* __restrict__ out)
{
  __shared__ float qs[NH * QROWS];        /* [h][row], pre-scaled      4 KB */
  __shared__ float ws[NH];                /* -2*wv                     1 KB */
  __shared__ float st[NK * QROWS];        /* [k][row] scores->probs   16 KB */
  __shared__ float pm[16], psm[16];
  __shared__ float part[4 * QROWS * ND];  /* split-k partials         32 KB */

  const int t  = threadIdx.x;
  const int q0 = blockIdx.x * QROWS;
  const int b  = blockIdx.y;

  {
    const float* qsrc = qp + ((size_t)b * NQ + q0) * NH;
    const int row = t >> 8, h = t & 255;
    qs[h * QROWS + row] = qsrc[t];        /* qsrc[row*NH+h] == qsrc[t] */
    if (t < NH) ws[t] = -2.0f * wvp[t];
  }
  __syncthreads();

  int vls[4];
  ff_vldec(vlraw, vls);
  const int vl = vls[b];

  /* ---- phase 1: scores, thread owns k = t (packed pairs) ---- */
  v2f a01 = {0.f, 0.f}, a23 = {0.f, 0.f};
  {
    const float* kvp = kp + (size_t)b * NH * NK + t;
    #pragma unroll 8
    for (int h = 0; h < NH; ++h) {
      float kv = kvp[(size_t)h * NK];
      v2f kv2; kv2.x = kv; kv2.y = kv;
      v2f q01 = *(const v2f*)(qs + h * QROWS);
      v2f q23 = *(const v2f*)(qs + h * QROWS + 2);
      float w = ws[h];
      v2f w2; w2.x = w; w2.y = w;
      v2f u01 = q01 + kv2;
      v2f u23 = q23 + kv2;
      v2f e01, e23;
      e01.x = __builtin_amdgcn_exp2f(u01.x);
      e01.y = __builtin_amdgcn_exp2f(u01.y);
      e23.x = __builtin_amdgcn_exp2f(u23.x);
      e23.y = __builtin_amdgcn_exp2f(u23.y);
      v2f one; one.x = 1.0f; one.y = 1.0f;
      v2f d01 = one + e01, d23 = one + e23;
      v2f r01, r23;
      r01.x = __builtin_amdgcn_rcpf(d01.x);
      r01.y = __builtin_amdgcn_rcpf(d01.y);
      r23.x = __builtin_amdgcn_rcpf(d23.x);
      r23.y = __builtin_amdgcn_rcpf(d23.y);
      a01 += w2 * r01;
      a23 += w2 * r23;
    }
  }
  {
    const bool okm = (t < vl);
    *(float4*)&st[t * 4] = make_float4(okm ? a01.x : -1e6f, okm ? a01.y : -1e6f,
                                       okm ? a23.x : -1e6f, okm ? a23.y : -1e6f);
  }
  __syncthreads();

  /* ---- phase 2: masked softmax, 4 waves per row ---- */
  {
    const int wid = t >> 6, lane = t & 63;
    const int row = wid >> 2, seg = wid & 3;
    const int kb = seg * 256 + lane;
    float v0 = st[(kb      ) * 4 + row];
    float v1 = st[(kb +  64) * 4 + row];
    float v2 = st[(kb + 128) * 4 + row];
    float v3 = st[(kb + 192) * 4 + row];
    float m = fmaxf(fmaxf(v0, v1), fmaxf(v2, v3));
    for (int o = 32; o; o >>= 1) m = fmaxf(m, __shfl_xor(m, o));
    if (lane == 0) pm[wid] = m;
    __syncthreads();
    m = fmaxf(fmaxf(pm[row*4+0], pm[row*4+1]), fmaxf(pm[row*4+2], pm[row*4+3]));
    float e0 = __builtin_amdgcn_exp2f((v0 - m) * L2E);
    float e1 = __builtin_amdgcn_exp2f((v1 - m) * L2E);
    float e2 = __builtin_amdgcn_exp2f((v2 - m) * L2E);
    float e3 = __builtin_amdgcn_exp2f((v3 - m) * L2E);
    float sm = e0 + e1 + e2 + e3;
    for (int o = 32; o; o >>= 1) sm += __shfl_xor(sm, o);
    if (lane == 0) psm[wid] = sm;
    __syncthreads();
    const float S = psm[row*4+0] + psm[row*4+1] + psm[row*4+2] + psm[row*4+3];
    const float rr = 1.0f / S;
    st[(kb      ) * 4 + row] = e0 * rr;
    st[(kb +  64) * 4 + row] = e1 * rr;
    st[(kb + 128) * 4 + row] = e2 * rr;
    st[(kb + 192) * 4 + row] = e3 * rr;
  }
  __syncthreads();

  /* ---- phase 3: PV, split-k quarters (packed); values read once ---- */
  {
    const int kq = t >> 8, c2 = (t & 255) * 2;
    const float* vb = vals + (size_t)b * NK * ND + c2;
    v2f o0 = {0.f,0.f}, o1 = {0.f,0.f}, o2 = {0.f,0.f}, o3 = {0.f,0.f};
    const int k0 = kq * 256;
    #pragma unroll 8
    for (int k = k0; k < k0 + 256; ++k) {
      v2f vv = *(const v2f*)(vb + (size_t)k * ND);
      float4 a = *(const float4*)&st[k * 4];
      v2f ax; ax.x = a.x; ax.y = a.x;
      v2f ay; ay.x = a.y; ay.y = a.y;
      v2f az; az.x = a.z; az.y = a.z;
      v2f aw; aw.x = a.w; aw.y = a.w;
      o0 += ax * vv; o1 += ay * vv; o2 += az * vv; o3 += aw * vv;
    }
    float* pp = &part[(size_t)kq * QROWS * ND + c2];
    *(v2f*)(pp         ) = o0;
    *(v2f*)(pp +     ND) = o1;
    *(v2f*)(pp + 2 * ND) = o2;
    *(v2f*)(pp + 3 * ND) = o3;
  }
  __syncthreads();
  {
    const int r = t >> 8, c2 = (t & 255) * 2;
    const float* pp = &part[(size_t)r * ND + c2];
    v2f s = {0.f, 0.f};
    #pragma unroll
    for (int kq = 0; kq < 4; ++kq) s += *(const v2f*)(pp + (size_t)kq * QROWS * ND);
    *(v2f*)(out + ((size_t)b * NQ + q0 + r) * ND + c2) = s;
  }
}

extern "C" void kernel_launch(void* const* d_in, const int* in_sizes, int n_in,
                              void* d_out, int out_size, void* d_ws, size_t ws_size,
                              hipStream_t stream) {
  const float* queries = (const float*)d_in[0];
  const float* keys    = (const float*)d_in[1];
  const float* values  = (const float*)d_in[2];
  const int*   vlens   = (const int*)d_in[3];
  const float* Wq      = (const float*)d_in[4];
  const float* Wk      = (const float*)d_in[5];
  const float* wv      = (const float*)d_in[6];
  float* out = (float*)d_out;               /* F32 OUTPUT */

  float* qp  = (float*)d_ws;                /* [B][Q][H]   1 MB, pre-scaled */
  float* kp  = qp  + (size_t)NB * NQ * NH;  /* [B][H][K]   4 MB, pre-scaled */
  float* wtq = kp  + (size_t)NB * NH * NK;  /* [D/4][H]x4  512 KB */
  float* wtk = wtq + (size_t)(ND / 4) * NH * 4; /*         512 KB */

  ff_wt  <<<dim3(128, 2), 256, 0, stream>>>(Wq, Wk, wtq, wtk);
  ff_proj<<<dim3((NB * (NQ + NK) / PJR) * (NH / PJH)), 256, 0, stream>>>(
      queries, keys, wtq, wtk, qp, kp);
  ff_attn<<<dim3(NQ / QROWS, NB), 1024, 0, stream>>>(qp, kp, values, vlens, wv, out);
}